// Round 1
// baseline (244.583 us; speedup 1.0000x reference)
//
#include <hip/hip_runtime.h>
#include <float.h>

#define HW    4096      // H*W
#define NC    64        // channels / latent dim
#define NK    1024      // codebook entries
#define NB    32        // batch
#define NPIX  (NB*HW)   // 131072 pixels
#define TOTAL (NPIX*NC) // 8388608 output elements of z_q
#define PPB   128       // pixels per block (32 per wave, 2 MFMA B-sets)

// bf16 hi/lo split score error bound ~1.4e-3 worst case; MARGIN 8e-3 gives
// >4x safety (validated rounds 4-9, absmax 0). gap2<MARGIN (incl. any exact
// fp32 tie) -> cooperative exact fp64 full rescan (~0.13%/pixel).
#define MARGIN 8e-3f

typedef __attribute__((ext_vector_type(8))) short short8;   // 8 bf16 (4 VGPRs)
typedef __attribute__((ext_vector_type(4))) float floatx4;  // MFMA acc

__device__ __forceinline__ unsigned short f2bf(float f) {   // fp32 -> bf16 RNE
    unsigned u = __float_as_uint(f);
    u += 0x7FFFu + ((u >> 16) & 1u);
    return (unsigned short)(u >> 16);
}
__device__ __forceinline__ float bf2f(unsigned short h) {
    return __uint_as_float(((unsigned)h) << 16);
}

// Prep: blocks 0..63 element-parallel bf16 hi/lo split, fully coalesced
// 16B-in / 8B-out. Blocks 64..67: fp64-accurate cnorm.
__global__ void vq_prep_kernel(const float* __restrict__ cb,
                               float* __restrict__ cnorm,
                               unsigned short* __restrict__ cb_hi,
                               unsigned short* __restrict__ cb_lo,
                               float* __restrict__ loss_out) {
    const int b = blockIdx.x;
    if (b < 64) {
        const int i = b * 256 + threadIdx.x;     // float4 index, 16384 total
        if (i == 0) loss_out[0] = 0.0f;
        float4 v = ((const float4*)cb)[i];
        unsigned short h0 = f2bf(v.x), h1 = f2bf(v.y),
                       h2 = f2bf(v.z), h3 = f2bf(v.w);
        unsigned short l0 = f2bf(v.x - bf2f(h0)), l1 = f2bf(v.y - bf2f(h1)),
                       l2 = f2bf(v.z - bf2f(h2)), l3 = f2bf(v.w - bf2f(h3));
        uint2 ph = make_uint2((unsigned)h0 | ((unsigned)h1 << 16),
                              (unsigned)h2 | ((unsigned)h3 << 16));
        uint2 pl = make_uint2((unsigned)l0 | ((unsigned)l1 << 16),
                              (unsigned)l2 | ((unsigned)l3 << 16));
        ((uint2*)cb_hi)[i] = ph;                 // coalesced 8B stores
        ((uint2*)cb_lo)[i] = pl;
    } else {
        const int k = (b - 64) * 256 + threadIdx.x;  // 0..1023
        const float4* r4 = (const float4*)(cb + (size_t)k * NC);
        double s = 0.0;
        #pragma unroll
        for (int j = 0; j < 16; ++j) {
            float4 v = r4[j];
            s = fma((double)v.x, (double)v.x, s);
            s = fma((double)v.y, (double)v.y, s);
            s = fma((double)v.z, (double)v.z, s);
            s = fma((double)v.w, (double)v.w, s);
        }
        cnorm[k] = (float)s;
    }
}

// Main: block = 256 threads / 4 waves / 128 pixels (32 per wave, 2 B-sets).
// R10 change: BARRIER-FREE sweep. The A-tile LDS double buffer (and its 64
// per-tile __syncthreads) is gone: the codebook (cb_hi+cb_lo = 256 KB) is
// L2-resident, so each lane streams its 4 A fragments (16B each, 64B-sector
// coalesced: row=pcol, chunk q / 4+q) straight from global through an
// explicit 2-tile register double buffer (named p/q bufs -> static indexing,
// no scratch; issue-after-consume gives ~1 tile of VMEM lookahead, far above
// L2 latency). Removes barrier coupling of the block's 4 waves (which sit on
// 4 different SIMDs contending with 3 other blocks each) and the
// global->LDS->reg round trip. LDS shrinks to cnorm + reduction scratch.
__global__ __launch_bounds__(256, 4) void vq_mfma_kernel(
        const float* __restrict__ z,
        const float* __restrict__ cb,
        const unsigned short* __restrict__ cb_hi,
        const unsigned short* __restrict__ cb_lo,
        const float* __restrict__ cnorm,
        float* __restrict__ zq,
        float* __restrict__ loss_out) {
    __shared__ alignas(16) float cn_lds[NK];   // 4 KB; rescan scratch aliases
    __shared__ int   finidx[PPB];
    __shared__ int   flags[PPB];
    __shared__ float redf[4];

    const int tid = threadIdx.x;
    const int g0  = blockIdx.x * PPB;
    const int bb  = g0 >> 12;
    const int pp0 = g0 & 4095;
    const float* zbase = z  + (size_t)bb * (NC * HW) + pp0;
    float*      zqbase = zq + (size_t)bb * (NC * HW) + pp0;

    // ---- stage cnorm -> LDS ----
    ((float4*)cn_lds)[tid] = ((const float4*)cnorm)[tid];

    const int lane = tid & 63;
    const int w    = tid >> 6;
    const int q    = lane >> 4;
    const int pcol = lane & 15;

    // ---- B fragments straight from global: 32 strided floats per lane ----
    // B[k][n]: n = this lane's pixel, k = q*8+t (kstep 0) / 32+q*8+t (kstep 1)
    float zraw[2][2][8];                 // [kstep][pixel set][t]
    #pragma unroll
    for (int ks = 0; ks < 2; ++ks)
        #pragma unroll
        for (int j = 0; j < 2; ++j)
            #pragma unroll
            for (int t = 0; t < 8; ++t)
                zraw[ks][j][t] = zbase[(size_t)(ks * 32 + q * 8 + t) * HW
                                       + (w * 32 + j * 16 + pcol)];
    short8 Bh[2][2], Bl[2][2];
    #pragma unroll
    for (int ks = 0; ks < 2; ++ks)
        #pragma unroll
        for (int j = 0; j < 2; ++j)
            #pragma unroll
            for (int t = 0; t < 8; ++t) {
                float v = -2.0f * zraw[ks][j][t];
                unsigned short h = f2bf(v);
                unsigned short l = f2bf(v - bf2f(h));
                Bh[ks][j][t] = (short)h;
                Bl[ks][j][t] = (short)l;
            }

    // ---- per-lane A-fragment global base addresses ----
    // A fragment for mfma_16x16x32: lane (q,pcol) needs code row (tile*16 +
    // pcol), k-chunk q (ah0 / al0) and 4+q (ah1 / al1); 16B contiguous each.
    // Per tile: +2048 B. Max offset 63*2048 + 15*128 + 64 + 48 + 16 = 128 KB,
    // exactly in bounds.
    const char* pAh = (const char*)cb_hi + pcol * 128 + q * 16;
    const char* pAl = (const char*)cb_lo + pcol * 128 + q * 16;

    __syncthreads();                     // cn_lds visible; ONLY sweep barrier

    float B1[2] = {FLT_MAX, FLT_MAX};
    float B2[2] = {FLT_MAX, FLT_MAX};
    int   I1[2] = {0, 0};

    auto tile_body = [&](short8 ah0, short8 ah1, short8 al0, short8 al1,
                         int tile) {
        const floatx4 cn4 = *(const floatx4*)&cn_lds[tile * 16 + q * 4];
        const int kb = tile * 16 + q * 4;
        #pragma unroll
        for (int j = 0; j < 2; ++j) {
            // score = cn + (-2z).e :  e_hi*z_hi + e_hi*z_lo + e_lo*z_hi
            floatx4 a0 = __builtin_amdgcn_mfma_f32_16x16x32_bf16(ah0, Bh[0][j], cn4, 0, 0, 0);
            floatx4 a1 = {0.f, 0.f, 0.f, 0.f};
            a1 = __builtin_amdgcn_mfma_f32_16x16x32_bf16(ah1, Bh[1][j], a1, 0, 0, 0);
            a0 = __builtin_amdgcn_mfma_f32_16x16x32_bf16(ah0, Bl[0][j], a0, 0, 0, 0);
            a1 = __builtin_amdgcn_mfma_f32_16x16x32_bf16(ah1, Bl[1][j], a1, 0, 0, 0);
            a0 = __builtin_amdgcn_mfma_f32_16x16x32_bf16(al0, Bh[0][j], a0, 0, 0, 0);
            a1 = __builtin_amdgcn_mfma_f32_16x16x32_bf16(al1, Bh[1][j], a1, 0, 0, 0);

            // C/D layout: code row = q*4+reg, pixel col = lane&15 (verified)
            #pragma unroll
            for (int i = 0; i < 4; ++i) {
                float s = a0[i] + a1[i];
                bool lt = s < B1[j];                 // strict: first min wins
                I1[j] = lt ? (kb + i) : I1[j];
                B2[j] = __builtin_amdgcn_fmed3f(s, B1[j], B2[j]);
                B1[j] = fminf(s, B1[j]);
            }
        }
    };

    // ---- sweep 64 code tiles, free-running, reg double buffer (p/q) ----
    #define LDA(H0, H1, L0, L1, T)                                          \
        H0 = *(const short8*)(pAh + (size_t)(T) * 2048);                    \
        H1 = *(const short8*)(pAh + (size_t)(T) * 2048 + 64);               \
        L0 = *(const short8*)(pAl + (size_t)(T) * 2048);                    \
        L1 = *(const short8*)(pAl + (size_t)(T) * 2048 + 64);

    short8 pH0, pH1, pL0, pL1, qH0, qH1, qL0, qL1;
    LDA(pH0, pH1, pL0, pL1, 0)
    LDA(qH0, qH1, qL0, qL1, 1)
    for (int t = 0; t < 64; t += 2) {
        tile_body(pH0, pH1, pL0, pL1, t);
        if (t < 62) { LDA(pH0, pH1, pL0, pL1, t + 2) }   // prefetch even
        tile_body(qH0, qH1, qL0, qL1, t + 1);
        if (t < 62) { LDA(qH0, qH1, qL0, qL1, t + 3) }   // prefetch odd
    }
    #undef LDA

    // ---- merge top-2 across the 4 lanes sharing each pixel (xor 16,32) ----
    #pragma unroll
    for (int j = 0; j < 2; ++j) {
        float b1 = B1[j], b2 = B2[j];
        int i1 = I1[j];
        #pragma unroll
        for (int d = 16; d <= 32; d <<= 1) {
            float ob1 = __shfl_xor(b1, d);
            float ob2 = __shfl_xor(b2, d);
            int   oi1 = __shfl_xor(i1, d);
            // second-smallest of {b1,b2,ob1,ob2}; equal b1s -> gap 0 -> rescan
            float nb2 = fminf(fmaxf(b1, ob1), fminf(b2, ob2));
            bool lt = (ob1 < b1) || (ob1 == b1 && oi1 < i1);
            b1 = lt ? ob1 : b1;
            i1 = lt ? oi1 : i1;
            b2 = nb2;
        }
        if (q == 0) {
            const int px = w * 32 + j * 16 + pcol;
            finidx[px] = i1;
            flags[px]  = (b2 - b1 < MARGIN) ? 1 : 0;
        }
    }
    int myflag = 0;
    __syncthreads();
    if (tid < PPB) myflag = flags[tid];
    const int nflag = __syncthreads_count(myflag);

    // ---- rare cooperative exact fp64 rescan (scratch aliases cn_lds) ----
    if (nflag > 0) {
        double* red_s = reinterpret_cast<double*>(cn_lds);       // 2 KB
        int*    red_i = reinterpret_cast<int*>(cn_lds + 512);    // 1 KB
        for (int p = 0; p < PPB; ++p) {
            if (flags[p]) {
                const float* zp = zbase + p;
                double bd = 1.0e300; int bi = 0;
                #pragma unroll 1
                for (int r = 0; r < 4; ++r) {
                    const int k = tid * 4 + r;
                    const float* rowp = cb + (size_t)k * NC;
                    double s = 0.0;
                    for (int c = 0; c < NC; ++c) {
                        double t = (double)zp[(size_t)c * HW] - (double)rowp[c];
                        s = fma(t, t, s);
                    }
                    if (s < bd) { bd = s; bi = k; }  // k increasing: first min
                }
                red_s[tid] = bd; red_i[tid] = bi;
                __syncthreads();
                if (tid < 64) {
                    double m = red_s[tid]; int mi = red_i[tid];
                    #pragma unroll
                    for (int t = 1; t < 4; ++t) {
                        double om = red_s[tid + 64 * t];
                        int    oi = red_i[tid + 64 * t];
                        if (om < m || (om == m && oi < mi)) { m = om; mi = oi; }
                    }
                    #pragma unroll
                    for (int off = 32; off > 0; off >>= 1) {
                        double om = __shfl_down(m, off);
                        int    oi = __shfl_down(mi, off);
                        if (om < m || (om == m && oi < mi)) { m = om; mi = oi; }
                    }
                    if (tid == 0) finidx[p] = mi;
                }
                __syncthreads();
            }
        }
        __syncthreads();
    }

    // ---- epilogue: gather exact fp32 code row -> z_q, loss SSE ----
    // 2 threads per pixel, 32 channels each.
    {
        const int p  = tid & (PPB - 1);
        const int qq = tid >> 7;             // 0..1
        const int fi = finidx[p];
        const float4* crow4 = (const float4*)(cb + (size_t)fi * NC) + qq * 8;
        float sse = 0.f;
        #pragma unroll
        for (int j = 0; j < 8; ++j) {
            const float4 qv = crow4[j];
            const size_t c0 = (size_t)(qq * 32 + 4 * j) * HW + p;
            const float z0 = zbase[c0];
            const float z1 = zbase[c0 + HW];
            const float z2 = zbase[c0 + 2 * (size_t)HW];
            const float z3 = zbase[c0 + 3 * (size_t)HW];
            zqbase[c0]                  = qv.x;   // coalesced across threads
            zqbase[c0 + HW]             = qv.y;
            zqbase[c0 + 2 * (size_t)HW] = qv.z;
            zqbase[c0 + 3 * (size_t)HW] = qv.w;
            float t0 = qv.x - z0, t1 = qv.y - z1, t2 = qv.z - z2, t3 = qv.w - z3;
            sse = fmaf(t0, t0, sse);
            sse = fmaf(t1, t1, sse);
            sse = fmaf(t2, t2, sse);
            sse = fmaf(t3, t3, sse);
        }
        #pragma unroll
        for (int off = 32; off > 0; off >>= 1) sse += __shfl_down(sse, off);
        if ((tid & 63) == 0) redf[tid >> 6] = sse;
        __syncthreads();
        if (tid == 0)
            atomicAdd(loss_out, (redf[0] + redf[1] + redf[2] + redf[3]) *
                                (1.25f / (float)TOTAL));
    }
}

extern "C" void kernel_launch(void* const* d_in, const int* in_sizes, int n_in,
                              void* d_out, int out_size, void* d_ws, size_t ws_size,
                              hipStream_t stream) {
    const float* z  = (const float*)d_in[0];   // [32, 64, 64, 64] fp32
    const float* cb = (const float*)d_in[1];   // [1024, 64] fp32
    float* out      = (float*)d_out;           // z_q ++ loss
    float* zqp      = out;
    float* loss     = out + TOTAL;

    // ws: cnorm fp32[1024] | cb_hi bf16[1024*64] | cb_lo bf16[1024*64]
    float* cnorm          = (float*)d_ws;
    unsigned short* cb_hi = (unsigned short*)((char*)d_ws + 4096);
    unsigned short* cb_lo = (unsigned short*)((char*)d_ws + 4096 + NK * NC * 2);

    vq_prep_kernel<<<68, 256, 0, stream>>>(cb, cnorm, cb_hi, cb_lo, loss);
    vq_mfma_kernel<<<NPIX / PPB, 256, 0, stream>>>(z, cb, cb_hi, cb_lo, cnorm,
                                                   zqp, loss);
}

// Round 2
// 173.612 us; speedup vs baseline: 1.4088x; 1.4088x over previous
//
#include <hip/hip_runtime.h>
#include <float.h>

#define HW    4096      // H*W
#define NC    64        // channels / latent dim
#define NK    1024      // codebook entries
#define NB    32        // batch
#define NPIX  (NB*HW)   // 131072 pixels
#define TOTAL (NPIX*NC) // 8388608 output elements of z_q
#define PPB   128       // pixels per block (32 per wave, 2 MFMA B-sets)

// bf16 hi/lo split score error bound ~1.4e-3 worst case; MARGIN 8e-3 gives
// >4x safety (validated rounds 4-9, absmax 0). gap2<MARGIN (incl. any exact
// fp32 tie) -> cooperative exact fp64 full rescan (~0.13%/pixel).
#define MARGIN 8e-3f

typedef __attribute__((ext_vector_type(8))) short short8;   // 8 bf16 (4 VGPRs)
typedef __attribute__((ext_vector_type(4))) float floatx4;  // MFMA acc

__device__ __forceinline__ unsigned short f2bf(float f) {   // fp32 -> bf16 RNE
    unsigned u = __float_as_uint(f);
    u += 0x7FFFu + ((u >> 16) & 1u);
    return (unsigned short)(u >> 16);
}
__device__ __forceinline__ float bf2f(unsigned short h) {
    return __uint_as_float(((unsigned)h) << 16);
}

// Prep: blocks 0..63 element-parallel bf16 hi/lo split, fully coalesced
// 16B-in / 8B-out. Blocks 64..67: fp64-accurate cnorm.
__global__ void vq_prep_kernel(const float* __restrict__ cb,
                               float* __restrict__ cnorm,
                               unsigned short* __restrict__ cb_hi,
                               unsigned short* __restrict__ cb_lo,
                               float* __restrict__ loss_out) {
    const int b = blockIdx.x;
    if (b < 64) {
        const int i = b * 256 + threadIdx.x;     // float4 index, 16384 total
        if (i == 0) loss_out[0] = 0.0f;
        float4 v = ((const float4*)cb)[i];
        unsigned short h0 = f2bf(v.x), h1 = f2bf(v.y),
                       h2 = f2bf(v.z), h3 = f2bf(v.w);
        unsigned short l0 = f2bf(v.x - bf2f(h0)), l1 = f2bf(v.y - bf2f(h1)),
                       l2 = f2bf(v.z - bf2f(h2)), l3 = f2bf(v.w - bf2f(h3));
        uint2 ph = make_uint2((unsigned)h0 | ((unsigned)h1 << 16),
                              (unsigned)h2 | ((unsigned)h3 << 16));
        uint2 pl = make_uint2((unsigned)l0 | ((unsigned)l1 << 16),
                              (unsigned)l2 | ((unsigned)l3 << 16));
        ((uint2*)cb_hi)[i] = ph;                 // coalesced 8B stores
        ((uint2*)cb_lo)[i] = pl;
    } else {
        const int k = (b - 64) * 256 + threadIdx.x;  // 0..1023
        const float4* r4 = (const float4*)(cb + (size_t)k * NC);
        double s = 0.0;
        #pragma unroll
        for (int j = 0; j < 16; ++j) {
            float4 v = r4[j];
            s = fma((double)v.x, (double)v.x, s);
            s = fma((double)v.y, (double)v.y, s);
            s = fma((double)v.z, (double)v.z, s);
            s = fma((double)v.w, (double)v.w, s);
        }
        cnorm[k] = (float)s;
    }
}

// Main: block = 256 threads / 4 waves / 128 pixels (32 per wave, 2 B-sets).
// R2: back to the verified LDS-staged sweep (R1's reg-pipeline collapsed:
// VGPR stayed 64 -> compiler sank the prefetch, exposing serial L2 latency).
// Two structural changes vs R0:
//   (a) 4 tiles per barrier interval -> 17 barriers instead of 64, so the
//       compiler's full vmcnt/lgkmcnt drain before each s_barrier is
//       amortized over 48 MFMAs.
//   (b) staging via __builtin_amdgcn_global_load_lds width=16: no
//       global->VGPR->LDS round trip, loads stay async until the one
//       per-interval drain. Swizzle kept both-sides-correct (rule #21):
//       LDS dest is LINEAR (slot = tid), the GLOBAL SOURCE is inverse-XOR-
//       swizzled, and the read side keeps R0's verified swizzled ridx --
//       identical bytes in identical slots as R0 (conflict-free, R8).
__global__ __launch_bounds__(256, 4) void vq_mfma_kernel(
        const float* __restrict__ z,
        const float* __restrict__ cb,
        const unsigned short* __restrict__ cb_hi,
        const unsigned short* __restrict__ cb_lo,
        const float* __restrict__ cnorm,
        float* __restrict__ zq,
        float* __restrict__ loss_out) {
    // [buf(2)][tile_in_interval(4)*256 + slot(256)] uint4 units, 32 KB.
    // Within one tile: slot = part*128 + row*8 + chunk^(row&7)  (R0 layout).
    __shared__ alignas(16) uint4  abuf[2][1024];
    __shared__ alignas(16) float  cn_lds[NK];   // 4 KB; rescan scratch aliases
    __shared__ int   finidx[PPB];
    __shared__ int   flags[PPB];
    __shared__ float redf[4];

    const int tid = threadIdx.x;
    const int g0  = blockIdx.x * PPB;
    const int bb  = g0 >> 12;
    const int pp0 = g0 & 4095;
    const float* zbase = z  + (size_t)bb * (NC * HW) + pp0;
    float*      zqbase = zq + (size_t)bb * (NC * HW) + pp0;

    // ---- stage cnorm -> LDS ----
    ((float4*)cn_lds)[tid] = ((const float4*)cnorm)[tid];

    const int lane = tid & 63;
    const int w    = tid >> 6;
    const int q    = lane >> 4;
    const int pcol = lane & 15;

    // ---- pre-swizzled global source for linear global_load_lds dest ----
    // Thread tid fills LDS slot tid (wave-uniform base + lane*16 -- exactly
    // what global_load_lds does). Slot (part,row,chunk) must hold global
    // chunk^(row&7), so the SOURCE index gets the XOR (involution).
    const int  sidx  = tid & 127;
    const int  spart = tid >> 7;
    const int  sswz  = (sidx & ~7) | ((sidx & 7) ^ ((sidx >> 3) & 7));
    const char* gsrc = (spart == 0 ? (const char*)cb_hi : (const char*)cb_lo)
                       + (size_t)sswz * 16;

    // issue one 4-tile interval of staging (async, no VGPR round trip)
    auto stage_iv = [&](int iv, int buf) {
        #pragma unroll
        for (int tt = 0; tt < 4; ++tt)
            __builtin_amdgcn_global_load_lds(
                (const __attribute__((address_space(1))) void*)
                    (gsrc + (size_t)iv * 8192 + (size_t)tt * 2048),
                (__attribute__((address_space(3))) void*)
                    &abuf[buf][tt * 256 + tid],
                16, 0, 0);
    };

    stage_iv(0, 0);   // interval 0 in flight; z-loads below cover its latency

    // ---- B fragments straight from global: 32 strided floats per lane ----
    // B[k][n]: n = this lane's pixel, k = q*8+t (kstep 0) / 32+q*8+t (kstep 1)
    float zraw[2][2][8];                 // [kstep][pixel set][t]
    #pragma unroll
    for (int ks = 0; ks < 2; ++ks)
        #pragma unroll
        for (int j = 0; j < 2; ++j)
            #pragma unroll
            for (int t = 0; t < 8; ++t)
                zraw[ks][j][t] = zbase[(size_t)(ks * 32 + q * 8 + t) * HW
                                       + (w * 32 + j * 16 + pcol)];
    short8 Bh[2][2], Bl[2][2];
    #pragma unroll
    for (int ks = 0; ks < 2; ++ks)
        #pragma unroll
        for (int j = 0; j < 2; ++j)
            #pragma unroll
            for (int t = 0; t < 8; ++t) {
                float v = -2.0f * zraw[ks][j][t];
                unsigned short h = f2bf(v);
                unsigned short l = f2bf(v - bf2f(h));
                Bh[ks][j][t] = (short)h;
                Bl[ks][j][t] = (short)l;
            }

    // per-lane fixed read offsets (uint4 units within one tile's 256 slots)
    const int ridx0 = pcol * 8 + (q ^ (pcol & 7));        // chunk q
    const int ridx1 = pcol * 8 + ((4 + q) ^ (pcol & 7));  // chunk 4+q

    __syncthreads();   // interval-0 staging drained (compiler vmcnt(0)) + cn_lds

    float B1[2] = {FLT_MAX, FLT_MAX};
    float B2[2] = {FLT_MAX, FLT_MAX};
    int   I1[2] = {0, 0};

    auto tile_body = [&](short8 ah0, short8 ah1, short8 al0, short8 al1,
                         int tile) {
        const floatx4 cn4 = *(const floatx4*)&cn_lds[tile * 16 + q * 4];
        const int kb = tile * 16 + q * 4;
        #pragma unroll
        for (int j = 0; j < 2; ++j) {
            // score = cn + (-2z).e :  e_hi*z_hi + e_hi*z_lo + e_lo*z_hi
            floatx4 a0 = __builtin_amdgcn_mfma_f32_16x16x32_bf16(ah0, Bh[0][j], cn4, 0, 0, 0);
            floatx4 a1 = {0.f, 0.f, 0.f, 0.f};
            a1 = __builtin_amdgcn_mfma_f32_16x16x32_bf16(ah1, Bh[1][j], a1, 0, 0, 0);
            a0 = __builtin_amdgcn_mfma_f32_16x16x32_bf16(ah0, Bl[0][j], a0, 0, 0, 0);
            a1 = __builtin_amdgcn_mfma_f32_16x16x32_bf16(ah1, Bl[1][j], a1, 0, 0, 0);
            a0 = __builtin_amdgcn_mfma_f32_16x16x32_bf16(al0, Bh[0][j], a0, 0, 0, 0);
            a1 = __builtin_amdgcn_mfma_f32_16x16x32_bf16(al1, Bh[1][j], a1, 0, 0, 0);

            // C/D layout: code row = q*4+reg, pixel col = lane&15 (verified)
            #pragma unroll
            for (int i = 0; i < 4; ++i) {
                float s = a0[i] + a1[i];
                bool lt = s < B1[j];                 // strict: first min wins
                I1[j] = lt ? (kb + i) : I1[j];
                B2[j] = __builtin_amdgcn_fmed3f(s, B1[j], B2[j]);
                B1[j] = fminf(s, B1[j]);
            }
        }
    };

    // ---- sweep 64 code tiles as 16 intervals of 4, double-buffered ----
    // One barrier per interval: drain amortized over 48 MFMA. Write-after-
    // read safe: buf^1 was last read in interval iv-1, whose end barrier
    // precedes these stores.
    for (int iv = 0; iv < 16; ++iv) {
        if (iv < 15) stage_iv(iv + 1, (iv + 1) & 1);
        const short8* Abase = (const short8*)&abuf[iv & 1][0];
        #pragma unroll
        for (int tt = 0; tt < 4; ++tt) {
            const short8* A = Abase + tt * 256;
            short8 ah0 = A[ridx0];
            short8 ah1 = A[ridx1];
            short8 al0 = A[128 + ridx0];
            short8 al1 = A[128 + ridx1];
            tile_body(ah0, ah1, al0, al1, iv * 4 + tt);
        }
        __syncthreads();
    }

    // ---- merge top-2 across the 4 lanes sharing each pixel (xor 16,32) ----
    #pragma unroll
    for (int j = 0; j < 2; ++j) {
        float b1 = B1[j], b2 = B2[j];
        int i1 = I1[j];
        #pragma unroll
        for (int d = 16; d <= 32; d <<= 1) {
            float ob1 = __shfl_xor(b1, d);
            float ob2 = __shfl_xor(b2, d);
            int   oi1 = __shfl_xor(i1, d);
            // second-smallest of {b1,b2,ob1,ob2}; equal b1s -> gap 0 -> rescan
            float nb2 = fminf(fmaxf(b1, ob1), fminf(b2, ob2));
            bool lt = (ob1 < b1) || (ob1 == b1 && oi1 < i1);
            b1 = lt ? ob1 : b1;
            i1 = lt ? oi1 : i1;
            b2 = nb2;
        }
        if (q == 0) {
            const int px = w * 32 + j * 16 + pcol;
            finidx[px] = i1;
            flags[px]  = (b2 - b1 < MARGIN) ? 1 : 0;
        }
    }
    int myflag = 0;
    __syncthreads();
    if (tid < PPB) myflag = flags[tid];
    const int nflag = __syncthreads_count(myflag);

    // ---- rare cooperative exact fp64 rescan (scratch aliases cn_lds) ----
    if (nflag > 0) {
        double* red_s = reinterpret_cast<double*>(cn_lds);       // 2 KB
        int*    red_i = reinterpret_cast<int*>(cn_lds + 512);    // 1 KB
        for (int p = 0; p < PPB; ++p) {
            if (flags[p]) {
                const float* zp = zbase + p;
                double bd = 1.0e300; int bi = 0;
                #pragma unroll 1
                for (int r = 0; r < 4; ++r) {
                    const int k = tid * 4 + r;
                    const float* rowp = cb + (size_t)k * NC;
                    double s = 0.0;
                    for (int c = 0; c < NC; ++c) {
                        double t = (double)zp[(size_t)c * HW] - (double)rowp[c];
                        s = fma(t, t, s);
                    }
                    if (s < bd) { bd = s; bi = k; }  // k increasing: first min
                }
                red_s[tid] = bd; red_i[tid] = bi;
                __syncthreads();
                if (tid < 64) {
                    double m = red_s[tid]; int mi = red_i[tid];
                    #pragma unroll
                    for (int t = 1; t < 4; ++t) {
                        double om = red_s[tid + 64 * t];
                        int    oi = red_i[tid + 64 * t];
                        if (om < m || (om == m && oi < mi)) { m = om; mi = oi; }
                    }
                    #pragma unroll
                    for (int off = 32; off > 0; off >>= 1) {
                        double om = __shfl_down(m, off);
                        int    oi = __shfl_down(mi, off);
                        if (om < m || (om == m && oi < mi)) { m = om; mi = oi; }
                    }
                    if (tid == 0) finidx[p] = mi;
                }
                __syncthreads();
            }
        }
        __syncthreads();
    }

    // ---- epilogue: gather exact fp32 code row -> z_q, loss SSE ----
    // 2 threads per pixel, 32 channels each.
    {
        const int p  = tid & (PPB - 1);
        const int qq = tid >> 7;             // 0..1
        const int fi = finidx[p];
        const float4* crow4 = (const float4*)(cb + (size_t)fi * NC) + qq * 8;
        float sse = 0.f;
        #pragma unroll
        for (int j = 0; j < 8; ++j) {
            const float4 qv = crow4[j];
            const size_t c0 = (size_t)(qq * 32 + 4 * j) * HW + p;
            const float z0 = zbase[c0];
            const float z1 = zbase[c0 + HW];
            const float z2 = zbase[c0 + 2 * (size_t)HW];
            const float z3 = zbase[c0 + 3 * (size_t)HW];
            zqbase[c0]                  = qv.x;   // coalesced across threads
            zqbase[c0 + HW]             = qv.y;
            zqbase[c0 + 2 * (size_t)HW] = qv.z;
            zqbase[c0 + 3 * (size_t)HW] = qv.w;
            float t0 = qv.x - z0, t1 = qv.y - z1, t2 = qv.z - z2, t3 = qv.w - z3;
            sse = fmaf(t0, t0, sse);
            sse = fmaf(t1, t1, sse);
            sse = fmaf(t2, t2, sse);
            sse = fmaf(t3, t3, sse);
        }
        #pragma unroll
        for (int off = 32; off > 0; off >>= 1) sse += __shfl_down(sse, off);
        if ((tid & 63) == 0) redf[tid >> 6] = sse;
        __syncthreads();
        if (tid == 0)
            atomicAdd(loss_out, (redf[0] + redf[1] + redf[2] + redf[3]) *
                                (1.25f / (float)TOTAL));
    }
}

extern "C" void kernel_launch(void* const* d_in, const int* in_sizes, int n_in,
                              void* d_out, int out_size, void* d_ws, size_t ws_size,
                              hipStream_t stream) {
    const float* z  = (const float*)d_in[0];   // [32, 64, 64, 64] fp32
    const float* cb = (const float*)d_in[1];   // [1024, 64] fp32
    float* out      = (float*)d_out;           // z_q ++ loss
    float* zqp      = out;
    float* loss     = out + TOTAL;

    // ws: cnorm fp32[1024] | cb_hi bf16[1024*64] | cb_lo bf16[1024*64]
    float* cnorm          = (float*)d_ws;
    unsigned short* cb_hi = (unsigned short*)((char*)d_ws + 4096);
    unsigned short* cb_lo = (unsigned short*)((char*)d_ws + 4096 + NK * NC * 2);

    vq_prep_kernel<<<68, 256, 0, stream>>>(cb, cnorm, cb_hi, cb_lo, loss);
    vq_mfma_kernel<<<NPIX / PPB, 256, 0, stream>>>(z, cb, cb_hi, cb_lo, cnorm,
                                                   zqp, loss);
}